// Round 1
// baseline (1457.846 us; speedup 1.0000x reference)
//
#include <hip/hip_runtime.h>

#define NN 262144
#define EE (3 * NN)
#define HID 32
#define NB 58              // useful nodes per block
#define RR 64              // rows per block = NB + 6 halo
#define NBLK ((NN + NB - 1) / NB)   // 4520

// ---------------- norm reduction ----------------
__global__ void zero_ws_kernel(float* ws) { ws[0] = 0.f; }

__global__ __launch_bounds__(256) void sumsq_kernel(const float4* __restrict__ e4,
                                                    float* __restrict__ ws) {
    int i = blockIdx.x * blockDim.x + threadIdx.x;   // EE/4 threads exactly
    float4 v = e4[i];
    float s = v.x * v.x + v.y * v.y + v.z * v.z + v.w * v.w;
#pragma unroll
    for (int off = 32; off > 0; off >>= 1) s += __shfl_down(s, off, 64);
    if ((threadIdx.x & 63) == 0) atomicAdd(ws, s);
}

// ---------------- fused GNN ----------------
// Block: 256 threads = 4 waves. Wave w owns output columns [8w, 8w+8).
// LDS column-major: act[c*RR + row]; row<->lane => conflict-free.
__global__ __launch_bounds__(256) void gnn_kernel(
    const float* __restrict__ nodes, const float* __restrict__ edges,
    const int* __restrict__ receivers, const int* __restrict__ senders,
    const float* __restrict__ lhs_edges,
    const float* __restrict__ neW1, const float* __restrict__ neb1,
    const float* __restrict__ neW2, const float* __restrict__ neb2,
    const float* __restrict__ eeW1, const float* __restrict__ eeb1,
    const float* __restrict__ eeW2, const float* __restrict__ eeb2,
    const float* __restrict__ mpWe, const float* __restrict__ mpbe,
    const float* __restrict__ mpWn, const float* __restrict__ mpbn,
    const float* __restrict__ edW1, const float* __restrict__ edb1,
    const float* __restrict__ edW2, const float* __restrict__ edb2,
    const float* __restrict__ ws, float* __restrict__ out)
{
    __shared__ float s_n[HID * RR];
    __shared__ float s_e0[HID * RR];
    __shared__ float s_e1[HID * RR];
    __shared__ float s_e2[HID * RR];

    const int tid = threadIdx.x;
    const int lane = tid & 63;
    const int wv = __builtin_amdgcn_readfirstlane(tid >> 6);      // wave id, uniform
    const int cb = __builtin_amdgcn_readfirstlane((tid >> 6) * 8); // column base, uniform
    const int s0 = blockIdx.x * NB;

    const float norm = sqrtf(ws[0]);
    const float inv_norm = 1.f / norm;

    // ---- encoders: wave0 -> n rows, waves 1..3 -> e0/e1/e2 rows ----
    {
        int g = s0 - 3 + lane;                 // global node for this row
        int gm = g < 0 ? g + NN : (g >= NN ? g - NN : g);
        float x;
        const float *W1, *b1, *W2, *b2;
        float* dst;
        if (wv == 0) {
            x = nodes[gm];
            W1 = neW1; b1 = neb1; W2 = neW2; b2 = neb2;
            dst = s_n;
        } else {
            x = edges[(wv - 1) * NN + gm] * inv_norm;
            W1 = eeW1; b1 = eeb1; W2 = eeW2; b2 = eeb2;
            dst = (wv == 1) ? s_e0 : (wv == 2) ? s_e1 : s_e2;
        }
        float h1[HID];
#pragma unroll
        for (int c = 0; c < HID; ++c) h1[c] = fmaxf(fmaf(x, W1[c], b1[c]), 0.f);
        float acc[HID];
#pragma unroll
        for (int c = 0; c < HID; ++c) acc[c] = b2[c];
        for (int k = 0; k < HID; ++k) {
            float hk = h1[k];
#pragma unroll
            for (int c = 0; c < HID; ++c) acc[c] = fmaf(hk, W2[k * HID + c], acc[c]);
        }
#pragma unroll
        for (int c = 0; c < HID; ++c) dst[c * RR + lane] = acc[c];
    }
    __syncthreads();

    // ---- 3 message-passing rounds ----
    for (int r = 0; r < 3; ++r) {
        // edge phase: each wave computes cols [cb,cb+8) for all 3 edge types, row=lane
        float acc[3][8];
#pragma unroll
        for (int t = 0; t < 3; ++t) {
            const float* ep = (t == 0) ? s_e0 : (t == 1) ? s_e1 : s_e2;
            const int j = lane;
            const int jp = (j + 1) & 63;        // halo rows become invalid; never read out
            const int sj = (t == 2) ? jp : j;   // sender row
            const int rj = (t == 1) ? jp : j;   // receiver row
#pragma unroll
            for (int cc = 0; cc < 8; ++cc) acc[t][cc] = mpbe[cb + cc];
            for (int k = 0; k < HID; ++k) {
                float v = ep[k * RR + j];
#pragma unroll
                for (int cc = 0; cc < 8; ++cc)
                    acc[t][cc] = fmaf(v, mpWe[k * HID + cb + cc], acc[t][cc]);
            }
            for (int k = 0; k < HID; ++k) {
                float v = s_n[k * RR + sj];
#pragma unroll
                for (int cc = 0; cc < 8; ++cc)
                    acc[t][cc] = fmaf(v, mpWe[(HID + k) * HID + cb + cc], acc[t][cc]);
            }
            for (int k = 0; k < HID; ++k) {
                float v = s_n[k * RR + rj];
#pragma unroll
                for (int cc = 0; cc < 8; ++cc)
                    acc[t][cc] = fmaf(v, mpWe[(2 * HID + k) * HID + cb + cc], acc[t][cc]);
            }
        }
        __syncthreads();   // all reads of old e done
#pragma unroll
        for (int t = 0; t < 3; ++t) {
            float* ep = (t == 0) ? s_e0 : (t == 1) ? s_e1 : s_e2;
#pragma unroll
            for (int cc = 0; cc < 8; ++cc)
                ep[(cb + cc) * RR + lane] = fmaxf(acc[t][cc], 0.f);
        }
        __syncthreads();

        if (r < 2) {  // round-3 node update is never consumed -> skip
            float na[8];
#pragma unroll
            for (int cc = 0; cc < 8; ++cc) na[cc] = mpbn[cb + cc];
            const int j = lane, jm = (lane - 1) & 63;
            for (int k = 0; k < HID; ++k) {
                float v = s_n[k * RR + j];
#pragma unroll
                for (int cc = 0; cc < 8; ++cc)
                    na[cc] = fmaf(v, mpWn[k * HID + cb + cc], na[cc]);
            }
            for (int k = 0; k < HID; ++k) {
                // agg[j] = e_self[j] + e_fwd[j-1] + e_bwd[j]  (receivers == j)
                float v = s_e0[k * RR + j] + s_e1[k * RR + jm] + s_e2[k * RR + j];
#pragma unroll
                for (int cc = 0; cc < 8; ++cc)
                    na[cc] = fmaf(v, mpWn[(HID + k) * HID + cb + cc], na[cc]);
            }
            __syncthreads();  // all reads of old n done
#pragma unroll
            for (int cc = 0; cc < 8; ++cc)
                s_n[(cb + cc) * RR + j] = fmaxf(na[cc], 0.f);
            __syncthreads();
        }
    }

    // ---- bi-edge average + decoder layer 1 (h1 -> s_n, n is dead now) ----
    {
        float acc[8];
        const int j = lane;
#pragma unroll
        for (int cc = 0; cc < 8; ++cc) acc[cc] = edb1[cb + cc];
        for (int k = 0; k < HID; ++k) {
            float v = 0.5f * (s_e1[k * RR + j] + s_e2[k * RR + j]);
#pragma unroll
            for (int cc = 0; cc < 8; ++cc)
                acc[cc] = fmaf(v, edW1[k * HID + cb + cc], acc[cc]);
        }
#pragma unroll
        for (int cc = 0; cc < 8; ++cc)
            s_n[(cb + cc) * RR + j] = fmaxf(acc[cc], 0.f);
    }
    __syncthreads();

    // ---- decoder layer 2 + masked outputs ----
    if (tid < NB) {
        const int g = s0 + tid;
        if (g < NN) {
            const int j = 3 + tid;
            float dec = edb2[0];
            for (int k = 0; k < HID; ++k) dec = fmaf(s_n[k * RR + j], edW2[k], dec);
            dec *= norm;

            float* dataO = out;
            float* rowsO = out + EE;
            float* colsO = out + 2 * EE;

            // diagonal edge g: value overridden by sqrt(lhs_edges[g])
            {
                int s = senders[g], rc = receivers[g];
                bool m = s >= rc;
                dataO[g] = m ? sqrtf(lhs_edges[g]) : 0.f;
                rowsO[g] = m ? (float)s : 0.f;
                colsO[g] = m ? (float)rc : 0.f;
            }
            // forward edge N+g and backward edge 2N+g share the averaged value
            {
                int k1 = NN + g;
                int s = senders[k1], rc = receivers[k1];
                bool m = s >= rc;
                dataO[k1] = m ? dec : 0.f;
                rowsO[k1] = m ? (float)s : 0.f;
                colsO[k1] = m ? (float)rc : 0.f;
            }
            {
                int k2 = 2 * NN + g;
                int s = senders[k2], rc = receivers[k2];
                bool m = s >= rc;
                dataO[k2] = m ? dec : 0.f;
                rowsO[k2] = m ? (float)s : 0.f;
                colsO[k2] = m ? (float)rc : 0.f;
            }
        }
    }
}

extern "C" void kernel_launch(void* const* d_in, const int* in_sizes, int n_in,
                              void* d_out, int out_size, void* d_ws, size_t ws_size,
                              hipStream_t stream) {
    const float* nodes     = (const float*)d_in[0];
    const float* edges     = (const float*)d_in[1];
    const int*   receivers = (const int*)d_in[2];
    const int*   senders   = (const int*)d_in[3];
    const float* lhs_edges = (const float*)d_in[5];
    const float* neW1 = (const float*)d_in[9];
    const float* neb1 = (const float*)d_in[10];
    const float* neW2 = (const float*)d_in[11];
    const float* neb2 = (const float*)d_in[12];
    const float* eeW1 = (const float*)d_in[13];
    const float* eeb1 = (const float*)d_in[14];
    const float* eeW2 = (const float*)d_in[15];
    const float* eeb2 = (const float*)d_in[16];
    const float* mpWe = (const float*)d_in[17];
    const float* mpbe = (const float*)d_in[18];
    const float* mpWn = (const float*)d_in[19];
    const float* mpbn = (const float*)d_in[20];
    const float* edW1 = (const float*)d_in[21];
    const float* edb1 = (const float*)d_in[22];
    const float* edW2 = (const float*)d_in[23];
    const float* edb2 = (const float*)d_in[24];

    float* ws = (float*)d_ws;
    float* outp = (float*)d_out;

    hipLaunchKernelGGL(zero_ws_kernel, dim3(1), dim3(1), 0, stream, ws);
    hipLaunchKernelGGL(sumsq_kernel, dim3(EE / 1024), dim3(256), 0, stream,
                       (const float4*)edges, ws);
    hipLaunchKernelGGL(gnn_kernel, dim3(NBLK), dim3(256), 0, stream,
                       nodes, edges, receivers, senders, lhs_edges,
                       neW1, neb1, neW2, neb2, eeW1, eeb1, eeW2, eeb2,
                       mpWe, mpbe, mpWn, mpbn, edW1, edb1, edW2, edb2,
                       ws, outp);
}

// Round 2
// 206.440 us; speedup vs baseline: 7.0618x; 7.0618x over previous
//
#include <hip/hip_runtime.h>

#define NN 262144
#define EE (3 * NN)
#define HID 32
#define NB 58               // useful nodes per block
#define NROWS 65            // 64 live rows + 1 guard row (row 64, zeroed)
#define P 40                // LDS row pitch in halves (80 B, 16B-aligned, 2-way max conflict)
#define NBLK ((NN + NB - 1) / NB)   // 4520

typedef _Float16 half8 __attribute__((ext_vector_type(8)));
typedef _Float16 h2v   __attribute__((ext_vector_type(2)));
typedef float    f4v   __attribute__((ext_vector_type(4)));

#define MFMA16(a, b, c) __builtin_amdgcn_mfma_f32_16x16x32_f16((a), (b), (c), 0, 0, 0)

// ws layout: float norm_acc @ byte 0; f16 region @ byte 16:
//   [0,3072)    WeT[32][96]
//   [3072,5120) WnT[32][64]
//   [5120,6144) edW1T[32][32]
//   [6144,7168) neW2T[32][32]
//   [7168,8192) eeW2T[32][32]

__global__ __launch_bounds__(256) void setup_kernel(
    const float* __restrict__ mpWe, const float* __restrict__ mpWn,
    const float* __restrict__ edW1, const float* __restrict__ neW2,
    const float* __restrict__ eeW2, float* __restrict__ ws) {
    if (threadIdx.x == 0) ws[0] = 0.f;
    _Float16* h = (_Float16*)((char*)ws + 16);
    for (int i = threadIdx.x; i < 8192; i += 256) {
        _Float16 v;
        if (i < 3072)      { int n = i / 96,          k = i % 96;          v = (_Float16)mpWe[k * 32 + n]; }
        else if (i < 5120) { int j = i - 3072, n = j / 64, k = j % 64;     v = (_Float16)mpWn[k * 32 + n]; }
        else if (i < 6144) { int j = i - 5120, n = j / 32, k = j % 32;     v = (_Float16)edW1[k * 32 + n]; }
        else if (i < 7168) { int j = i - 6144, n = j / 32, k = j % 32;     v = (_Float16)neW2[k * 32 + n]; }
        else               { int j = i - 7168, n = j / 32, k = j % 32;     v = (_Float16)eeW2[k * 32 + n]; }
        h[i] = v;
    }
}

__global__ __launch_bounds__(256) void sumsq_kernel(const float4* __restrict__ e4,
                                                    float* __restrict__ ws) {
    int i = blockIdx.x * blockDim.x + threadIdx.x;   // EE/4 threads exactly
    float4 v = e4[i];
    float s = v.x * v.x + v.y * v.y + v.z * v.z + v.w * v.w;
#pragma unroll
    for (int off = 32; off > 0; off >>= 1) s += __shfl_down(s, off, 64);
    if ((threadIdx.x & 63) == 0) atomicAdd(ws, s);
}

// buffers: 0=n, 1=e0(self), 2=e1(fwd i->i+1), 3=e2(bwd i+1->i), 4=agg/avg scratch
__global__ __launch_bounds__(256) void gnn_kernel(
    const float* __restrict__ nodes, const float* __restrict__ edges,
    const int* __restrict__ receivers, const int* __restrict__ senders,
    const float* __restrict__ lhs_edges,
    const float* __restrict__ neW1, const float* __restrict__ neb1, const float* __restrict__ neb2,
    const float* __restrict__ eeW1, const float* __restrict__ eeb1, const float* __restrict__ eeb2,
    const float* __restrict__ mpbe, const float* __restrict__ mpbn,
    const float* __restrict__ edb1, const float* __restrict__ edb2,
    const float* __restrict__ edW2,
    const float* __restrict__ ws, float* __restrict__ out)
{
    __shared__ __align__(16) _Float16 sb[5][NROWS * P];

    const int tid  = threadIdx.x;
    const int lane = tid & 63;
    const int wv   = __builtin_amdgcn_readfirstlane(tid >> 6);
    const int q    = lane >> 4;      // quad within wave
    const int m    = lane & 15;      // row-in-tile for A, col-in-tile for B/C
    const int s0   = blockIdx.x * NB;

    const float norm = sqrtf(ws[0]);
    const float inv_norm = 1.f / norm;
    const _Float16* wt = (const _Float16*)((const char*)ws + 16);

    // ---- encoder layer 1: h1 = relu(x*W1 + b1), per wave -> own buffer, lane = row ----
    {
        _Float16* myb = sb[wv];
        int g = s0 - 3 + lane;
        int gm = g < 0 ? g + NN : (g >= NN ? g - NN : g);
        float x; const float *W1, *B1;
        if (wv == 0) { x = nodes[gm]; W1 = neW1; B1 = neb1; }
        else { x = edges[(wv - 1) * NN + gm] * inv_norm; W1 = eeW1; B1 = eeb1; }
#pragma unroll
        for (int c = 0; c < HID; c += 2) {
            h2v pk;
            pk[0] = (_Float16)fmaxf(fmaf(x, W1[c], B1[c]), 0.f);
            pk[1] = (_Float16)fmaxf(fmaf(x, W1[c + 1], B1[c + 1]), 0.f);
            *(h2v*)&myb[lane * P + c] = pk;
        }
    }
    // zero guard row 64 of all 5 buffers (read when roff=1 on last tile; must be finite)
    if (tid < 5 * P) sb[tid / P][64 * P + (tid % P)] = (_Float16)0.f;
    __syncthreads();

    // ---- encoder layer 2 (MFMA, in-place, no relu): act = h1 @ W2 + b2 ----
    {
        _Float16* myb = sb[wv];
        const float* B2 = (wv == 0) ? neb2 : eeb2;
        const float b2v0 = B2[m], b2v1 = B2[16 + m];
        const _Float16* w2t = wt + 6144 + (wv == 0 ? 0 : 1024);
        half8 bW2_0 = *(const half8*)(w2t + m * 32 + q * 8);
        half8 bW2_1 = *(const half8*)(w2t + (16 + m) * 32 + q * 8);
#pragma unroll
        for (int rt = 0; rt < 4; ++rt) {
            half8 a = *(const half8*)&myb[(rt * 16 + m) * P + q * 8];
            f4v z = {0.f, 0.f, 0.f, 0.f};
            f4v c0 = MFMA16(a, bW2_0, z);
            f4v c1 = MFMA16(a, bW2_1, z);
#pragma unroll
            for (int rg = 0; rg < 4; ++rg) {
                int row = rt * 16 + q * 4 + rg;
                myb[row * P + m]      = (_Float16)(c0[rg] + b2v0);
                myb[row * P + 16 + m] = (_Float16)(c1[rg] + b2v1);
            }
        }
    }

    // ---- resident B-fragments + per-lane biases for the MP rounds ----
    half8 fWe[3][2], fWn[2][2], fW1[2];
#pragma unroll
    for (int s = 0; s < 3; ++s)
#pragma unroll
        for (int ct = 0; ct < 2; ++ct)
            fWe[s][ct] = *(const half8*)(wt + (ct * 16 + m) * 96 + s * 32 + q * 8);
#pragma unroll
    for (int s = 0; s < 2; ++s)
#pragma unroll
        for (int ct = 0; ct < 2; ++ct)
            fWn[s][ct] = *(const half8*)(wt + 3072 + (ct * 16 + m) * 64 + s * 32 + q * 8);
#pragma unroll
    for (int ct = 0; ct < 2; ++ct)
        fW1[ct] = *(const half8*)(wt + 5120 + (ct * 16 + m) * 32 + q * 8);

    const float bev0 = mpbe[m], bev1 = mpbe[16 + m];
    const float bnv0 = mpbn[m], bnv1 = mpbn[16 + m];
    const float b1v0 = edb1[m], b1v1 = edb1[16 + m];

    __syncthreads();

    // ---- 3 message-passing rounds ----
    for (int r = 0; r < 3; ++r) {
        f4v acc[3][2];
#pragma unroll
        for (int i3 = 0; i3 < 3; ++i3) {
            acc[i3][0] = (f4v){0.f, 0.f, 0.f, 0.f};
            acc[i3][1] = (f4v){0.f, 0.f, 0.f, 0.f};
            const int p = wv * 3 + i3;
            const int t = p >> 2, rt = p & 3;   // edge type, row-tile
#pragma unroll
            for (int s = 0; s < 3; ++s) {
                const _Float16* ab;
                int roff;
                if (s == 0)      { ab = sb[1 + t]; roff = 0; }            // e_t
                else if (s == 1) { ab = sb[0]; roff = (t == 2) ? 1 : 0; } // n[senders]
                else             { ab = sb[0]; roff = (t == 1) ? 1 : 0; } // n[receivers]
                half8 a = *(const half8*)&ab[(rt * 16 + m + roff) * P + q * 8];
                acc[i3][0] = MFMA16(a, fWe[s][0], acc[i3][0]);
                acc[i3][1] = MFMA16(a, fWe[s][1], acc[i3][1]);
            }
        }
        __syncthreads();   // all reads of old e,n done
#pragma unroll
        for (int i3 = 0; i3 < 3; ++i3) {
            const int p = wv * 3 + i3;
            const int t = p >> 2, rt = p & 3;
            _Float16* eb = sb[1 + t];
#pragma unroll
            for (int rg = 0; rg < 4; ++rg) {
                int row = rt * 16 + q * 4 + rg;
                eb[row * P + m]      = (_Float16)fmaxf(acc[i3][0][rg] + bev0, 0.f);
                eb[row * P + 16 + m] = (_Float16)fmaxf(acc[i3][1][rg] + bev1, 0.f);
            }
        }
        __syncthreads();   // new e visible

        if (r < 2) {
            // agg[j] = e0[j] + e1[j-1] + e2[j]  (f16x2 packed)
#pragma unroll
            for (int it = 0; it < 4; ++it) {
                int idx = tid + it * 256;          // 0..1023 = 64 rows x 16 col-words
                int row = idx >> 4, cw = (idx & 15) * 2;
                int rowm = row ? row - 1 : 0;      // row 0 is invalid anyway
                h2v v = *(const h2v*)&sb[1][row * P + cw];
                v = v + *(const h2v*)&sb[2][rowm * P + cw];
                v = v + *(const h2v*)&sb[3][row * P + cw];
                *(h2v*)&sb[4][row * P + cw] = v;
            }
            __syncthreads();   // agg visible
            f4v na0 = {0.f, 0.f, 0.f, 0.f}, na1 = {0.f, 0.f, 0.f, 0.f};
#pragma unroll
            for (int s = 0; s < 2; ++s) {
                const _Float16* ab = s ? sb[4] : sb[0];
                half8 a = *(const half8*)&ab[(wv * 16 + m) * P + q * 8];
                na0 = MFMA16(a, fWn[s][0], na0);
                na1 = MFMA16(a, fWn[s][1], na1);
            }
            __syncthreads();   // all reads of old n done
#pragma unroll
            for (int rg = 0; rg < 4; ++rg) {
                int row = wv * 16 + q * 4 + rg;
                sb[0][row * P + m]      = (_Float16)fmaxf(na0[rg] + bnv0, 0.f);
                sb[0][row * P + 16 + m] = (_Float16)fmaxf(na1[rg] + bnv1, 0.f);
            }
            __syncthreads();   // new n visible
        }
    }

    // ---- bi-edge average into sb[4] ----
#pragma unroll
    for (int it = 0; it < 4; ++it) {
        int idx = tid + it * 256;
        int row = idx >> 4, cw = (idx & 15) * 2;
        h2v v = *(const h2v*)&sb[2][row * P + cw] + *(const h2v*)&sb[3][row * P + cw];
        h2v hh; hh[0] = (_Float16)0.5f; hh[1] = (_Float16)0.5f;
        *(h2v*)&sb[4][row * P + cw] = v * hh;
    }
    __syncthreads();

    // ---- decoder layer 1 (MFMA): h = relu(avg @ edW1 + edb1) -> sb[1] (e0 is dead) ----
    {
        f4v z = {0.f, 0.f, 0.f, 0.f};
        half8 a = *(const half8*)&sb[4][(wv * 16 + m) * P + q * 8];
        f4v h0 = MFMA16(a, fW1[0], z);
        f4v h1 = MFMA16(a, fW1[1], z);
#pragma unroll
        for (int rg = 0; rg < 4; ++rg) {
            int row = wv * 16 + q * 4 + rg;
            sb[1][row * P + m]      = (_Float16)fmaxf(h0[rg] + b1v0, 0.f);
            sb[1][row * P + 16 + m] = (_Float16)fmaxf(h1[rg] + b1v1, 0.f);
        }
    }
    __syncthreads();

    // ---- decoder layer 2 + masked outputs; thread tid handles row tid, node s0+tid-3 ----
    if (tid >= 3 && tid < 3 + NB) {
        const int g = s0 + tid - 3;
        if (g < NN) {
            const int row = tid;
            float dec = edb2[0];
#pragma unroll
            for (int cw = 0; cw < HID; cw += 2) {
                h2v v = *(const h2v*)&sb[1][row * P + cw];
                dec = fmaf((float)v[0], edW2[cw], dec);
                dec = fmaf((float)v[1], edW2[cw + 1], dec);
            }
            dec *= norm;

            float* dataO = out;
            float* rowsO = out + EE;
            float* colsO = out + 2 * EE;
            {   // diagonal (self) edge: value overridden by sqrt(lhs_edges[g])
                int s = senders[g], rc = receivers[g];
                bool msk = s >= rc;
                dataO[g] = msk ? sqrtf(lhs_edges[g]) : 0.f;
                rowsO[g] = msk ? (float)s : 0.f;
                colsO[g] = msk ? (float)rc : 0.f;
            }
            {
                int k1 = NN + g;
                int s = senders[k1], rc = receivers[k1];
                bool msk = s >= rc;
                dataO[k1] = msk ? dec : 0.f;
                rowsO[k1] = msk ? (float)s : 0.f;
                colsO[k1] = msk ? (float)rc : 0.f;
            }
            {
                int k2 = 2 * NN + g;
                int s = senders[k2], rc = receivers[k2];
                bool msk = s >= rc;
                dataO[k2] = msk ? dec : 0.f;
                rowsO[k2] = msk ? (float)s : 0.f;
                colsO[k2] = msk ? (float)rc : 0.f;
            }
        }
    }
}

extern "C" void kernel_launch(void* const* d_in, const int* in_sizes, int n_in,
                              void* d_out, int out_size, void* d_ws, size_t ws_size,
                              hipStream_t stream) {
    const float* nodes     = (const float*)d_in[0];
    const float* edges     = (const float*)d_in[1];
    const int*   receivers = (const int*)d_in[2];
    const int*   senders   = (const int*)d_in[3];
    const float* lhs_edges = (const float*)d_in[5];
    const float* neW1 = (const float*)d_in[9];
    const float* neb1 = (const float*)d_in[10];
    const float* neW2 = (const float*)d_in[11];
    const float* neb2 = (const float*)d_in[12];
    const float* eeW1 = (const float*)d_in[13];
    const float* eeb1 = (const float*)d_in[14];
    const float* eeW2 = (const float*)d_in[15];
    const float* eeb2 = (const float*)d_in[16];
    const float* mpWe = (const float*)d_in[17];
    const float* mpbe = (const float*)d_in[18];
    const float* mpWn = (const float*)d_in[19];
    const float* mpbn = (const float*)d_in[20];
    const float* edW1 = (const float*)d_in[21];
    const float* edb1 = (const float*)d_in[22];
    const float* edW2 = (const float*)d_in[23];
    const float* edb2 = (const float*)d_in[24];

    float* ws   = (float*)d_ws;
    float* outp = (float*)d_out;

    hipLaunchKernelGGL(setup_kernel, dim3(1), dim3(256), 0, stream,
                       mpWe, mpWn, edW1, neW2, eeW2, ws);
    hipLaunchKernelGGL(sumsq_kernel, dim3(EE / 1024), dim3(256), 0, stream,
                       (const float4*)edges, ws);
    hipLaunchKernelGGL(gnn_kernel, dim3(NBLK), dim3(256), 0, stream,
                       nodes, edges, receivers, senders, lhs_edges,
                       neW1, neb1, neb2, eeW1, eeb1, eeb2,
                       mpbe, mpbn, edb1, edb2, edW2,
                       ws, outp);
}

// Round 4
// 192.440 us; speedup vs baseline: 7.5756x; 1.0728x over previous
//
#include <hip/hip_runtime.h>

#define NN 262144
#define EE (3 * NN)
#define HID 32
#define NB 122              // useful nodes per block
#define RP 130              // phys rows: 1 guard + 128 + 1 guard
#define P 40                // LDS row pitch in halves (80 B)
#define NBLK ((NN + NB - 1) / NB)   // 2149

typedef _Float16 half8 __attribute__((ext_vector_type(8)));
typedef _Float16 h2v   __attribute__((ext_vector_type(2)));
typedef float    f4v   __attribute__((ext_vector_type(4)));

#define MFMA16(a, b, c) __builtin_amdgcn_mfma_f32_16x16x32_f16((a), (b), (c), 0, 0, 0)

// pack two f32 -> f16x2 (round-toward-zero pair convert), bit-cast to our h2v
static __device__ __forceinline__ h2v pk2(float a, float b) {
    return __builtin_bit_cast(h2v, __builtin_amdgcn_cvt_pkrtz(a, b));
}

// slot s holds original feature forig(s); pairs (2m,2m+1) = orig (m, m+16)
__host__ __device__ __forceinline__ int forig(int p) { return (p >> 1) + 16 * (p & 1); }

// ws: float norm_acc @0; f16 wt @byte16:
//  [0,3072)    We'   frag[c][p], p = K-slot over 96 (per-32 permuted)
//  [3072,4096) WeSum = We[32:64]+We[64:96] (self-edge fold)
//  [4096,5120) WnTop   [5120,6144) WnBot
//  [6144,7168) edW1'   [7168,8192) neW2'   [8192,9216) eeW2'
__global__ __launch_bounds__(256) void setup_kernel(
    const float* __restrict__ mpWe, const float* __restrict__ mpWn,
    const float* __restrict__ edW1, const float* __restrict__ neW2,
    const float* __restrict__ eeW2, float* __restrict__ ws) {
    int i = blockIdx.x * 256 + threadIdx.x;
    if (i == 0) ws[0] = 0.f;
    if (i >= 9216) return;
    _Float16* wt = (_Float16*)((char*)ws + 16);
    float v;
    if (i < 3072)      { int c = i / 96, p = i % 96; int k = (p >> 5) * 32 + forig(p & 31); v = mpWe[k * 32 + c]; }
    else if (i < 4096) { int j = i - 3072, c = j / 32, p = j % 32; int fo = forig(p);
                         v = mpWe[(32 + fo) * 32 + c] + mpWe[(64 + fo) * 32 + c]; }
    else if (i < 5120) { int j = i - 4096, c = j / 32, p = j % 32; v = mpWn[forig(p) * 32 + c]; }
    else if (i < 6144) { int j = i - 5120, c = j / 32, p = j % 32; v = mpWn[(32 + forig(p)) * 32 + c]; }
    else if (i < 7168) { int j = i - 6144, c = j / 32, p = j % 32; v = edW1[forig(p) * 32 + c]; }
    else if (i < 8192) { int j = i - 7168, c = j / 32, p = j % 32; v = neW2[forig(p) * 32 + c]; }
    else               { int j = i - 8192, c = j / 32, p = j % 32; v = eeW2[forig(p) * 32 + c]; }
    wt[i] = (_Float16)v;
}

__global__ __launch_bounds__(256) void sumsq_kernel(const float4* __restrict__ e4,
                                                    float* __restrict__ ws) {
    int i = blockIdx.x * blockDim.x + threadIdx.x;   // EE/4 threads exactly
    float4 v = e4[i];
    float s = v.x * v.x + v.y * v.y + v.z * v.z + v.w * v.w;
#pragma unroll
    for (int off = 32; off > 0; off >>= 1) s += __shfl_down(s, off, 64);
    if ((threadIdx.x & 63) == 0) atomicAdd(ws, s);
}

// buffers: 0=n, 1=e0(self), 2=e1(fwd i->i+1), 3=e2(bwd i+1->i)
// phys row = logical j + 1; logical j <-> global node s0 - 3 + j
__global__ __launch_bounds__(512, 4) void gnn_kernel(
    const float* __restrict__ nodes, const float* __restrict__ edges,
    const float* __restrict__ lhs_edges,
    const float* __restrict__ neW1, const float* __restrict__ neb1, const float* __restrict__ neb2,
    const float* __restrict__ eeW1, const float* __restrict__ eeb1, const float* __restrict__ eeb2,
    const float* __restrict__ mpbe, const float* __restrict__ mpbn,
    const float* __restrict__ edb1, const float* __restrict__ edb2,
    const float* __restrict__ edW2,
    const float* __restrict__ ws, float* __restrict__ out)
{
    __shared__ __align__(16) _Float16 sb[4][RP * P];

    const int tid  = threadIdx.x;
    const int lane = tid & 63;
    const int wv   = __builtin_amdgcn_readfirstlane(tid >> 6);
    const int q    = lane >> 4;
    const int m    = lane & 15;
    const int s0   = blockIdx.x * NB;

    const float norm = sqrtf(ws[0]);
    const float inv_norm = 1.f / norm;
    const _Float16* wt = (const _Float16*)((const char*)ws + 16);

    // ---- encoder layer 1: thread -> (buffer tid>>7, logical row tid&127) ----
    {
        int b = tid >> 7, r = tid & 127;
        int g = s0 - 3 + r;
        int gm = g < 0 ? g + NN : (g >= NN ? g - NN : g);
        float x; const float *W1, *B1;
        if (b == 0) { x = nodes[gm]; W1 = neW1; B1 = neb1; }
        else        { x = edges[(b - 1) * NN + gm] * inv_norm; W1 = eeW1; B1 = eeb1; }
        _Float16* dst = &sb[b][(r + 1) * P];
#pragma unroll
        for (int i = 0; i < 16; ++i) {
            float a0 = fmaxf(fmaf(x, W1[i],      B1[i]),      0.f);
            float a1 = fmaxf(fmaf(x, W1[i + 16], B1[i + 16]), 0.f);
            *(h2v*)&dst[2 * i] = pk2(a0, a1);
        }
    }
    // zero guard rows (phys 0 and 129) of all 4 buffers: 4*2*20 b32 writes
    if (tid < 160) {
        int b = tid / 40, k = tid % 40;
        int row = (k < 20) ? 0 : (RP - 1);
        h2v z = {};
        *(h2v*)&sb[b][row * P + (k % 20) * 2] = z;
    }
    __syncthreads();

    // ---- encoder layer 2 (MFMA, in-place, no relu): wave wv -> rt=wv, loop buffers ----
    {
        half8 fne0 = *(const half8*)(wt + 7168 + m * 32 + q * 8);
        half8 fne1 = *(const half8*)(wt + 7168 + (16 + m) * 32 + q * 8);
        half8 fee0 = *(const half8*)(wt + 8192 + m * 32 + q * 8);
        half8 fee1 = *(const half8*)(wt + 8192 + (16 + m) * 32 + q * 8);
        float bn0 = neb2[m], bn1 = neb2[16 + m];
        float be0 = eeb2[m], be1 = eeb2[16 + m];
#pragma unroll
        for (int b = 0; b < 4; ++b) {
            _Float16* buf = sb[b];
            half8 a = *(const half8*)&buf[(wv * 16 + m + 1) * P + q * 8];
            float bb0 = b ? be0 : bn0, bb1 = b ? be1 : bn1;
            f4v c0 = {bb0, bb0, bb0, bb0};
            f4v c1 = {bb1, bb1, bb1, bb1};
            c0 = MFMA16(a, b ? fee0 : fne0, c0);
            c1 = MFMA16(a, b ? fee1 : fne1, c1);
#pragma unroll
            for (int rg = 0; rg < 4; ++rg) {
                int row = wv * 16 + q * 4 + rg + 1;
                *(h2v*)&buf[row * P + 2 * m] = pk2(c0[rg], c1[rg]);
            }
        }
    }

    // ---- resident B-fragments + per-lane biases ----
    half8 fWe[3][2], fWeS[2], fWnT[2], fWnB[2], fW1[2];
#pragma unroll
    for (int s = 0; s < 3; ++s)
#pragma unroll
        for (int ct = 0; ct < 2; ++ct)
            fWe[s][ct] = *(const half8*)(wt + (ct * 16 + m) * 96 + s * 32 + q * 8);
#pragma unroll
    for (int ct = 0; ct < 2; ++ct) {
        fWeS[ct] = *(const half8*)(wt + 3072 + (ct * 16 + m) * 32 + q * 8);
        fWnT[ct] = *(const half8*)(wt + 4096 + (ct * 16 + m) * 32 + q * 8);
        fWnB[ct] = *(const half8*)(wt + 5120 + (ct * 16 + m) * 32 + q * 8);
        fW1[ct]  = *(const half8*)(wt + 6144 + (ct * 16 + m) * 32 + q * 8);
    }
    const float bev0 = mpbe[m], bev1 = mpbe[16 + m];
    const float bnv0 = mpbn[m], bnv1 = mpbn[16 + m];
    const float b1v0 = edb1[m], b1v1 = edb1[16 + m];

    __syncthreads();

    const int base = wv * 16 + m + 1;     // phys row of this lane's A-row j

    // ---- 3 message-passing rounds; wave wv owns row-tile wv for ALL 3 edge types ----
    for (int r = 0; r < 3; ++r) {
        half8 a_e0 = *(const half8*)&sb[1][base * P + q * 8];
        half8 a_e1 = *(const half8*)&sb[2][base * P + q * 8];
        half8 a_e2 = *(const half8*)&sb[3][base * P + q * 8];
        half8 a_nj  = *(const half8*)&sb[0][base * P + q * 8];
        half8 a_nj1 = *(const half8*)&sb[0][(base + 1) * P + q * 8];
        f4v acc0 = {bev0, bev0, bev0, bev0}, acc1 = {bev1, bev1, bev1, bev1};
        f4v acc2 = acc0, acc3 = acc1, acc4 = acc0, acc5 = acc1;
        // t0 (self): e0@We_e + n[j]@WeSum
        acc0 = MFMA16(a_e0, fWe[0][0], acc0); acc1 = MFMA16(a_e0, fWe[0][1], acc1);
        acc0 = MFMA16(a_nj, fWeS[0],   acc0); acc1 = MFMA16(a_nj, fWeS[1],   acc1);
        // t1 (fwd j->j+1): e1@We_e + n[j]@We_s + n[j+1]@We_r
        acc2 = MFMA16(a_e1,  fWe[0][0], acc2); acc3 = MFMA16(a_e1,  fWe[0][1], acc3);
        acc2 = MFMA16(a_nj,  fWe[1][0], acc2); acc3 = MFMA16(a_nj,  fWe[1][1], acc3);
        acc2 = MFMA16(a_nj1, fWe[2][0], acc2); acc3 = MFMA16(a_nj1, fWe[2][1], acc3);
        // t2 (bwd j+1->j): e2@We_e + n[j+1]@We_s + n[j]@We_r
        acc4 = MFMA16(a_e2,  fWe[0][0], acc4); acc5 = MFMA16(a_e2,  fWe[0][1], acc5);
        acc4 = MFMA16(a_nj1, fWe[1][0], acc4); acc5 = MFMA16(a_nj1, fWe[1][1], acc5);
        acc4 = MFMA16(a_nj,  fWe[2][0], acc4); acc5 = MFMA16(a_nj,  fWe[2][1], acc5);
        __syncthreads();   // all reads of old e,n done
#pragma unroll
        for (int rg = 0; rg < 4; ++rg) {
            int row = wv * 16 + q * 4 + rg + 1;
            *(h2v*)&sb[1][row * P + 2 * m] = pk2(fmaxf(acc0[rg], 0.f), fmaxf(acc1[rg], 0.f));
            *(h2v*)&sb[2][row * P + 2 * m] = pk2(fmaxf(acc2[rg], 0.f), fmaxf(acc3[rg], 0.f));
            *(h2v*)&sb[3][row * P + 2 * m] = pk2(fmaxf(acc4[rg], 0.f), fmaxf(acc5[rg], 0.f));
        }
        __syncthreads();   // new e visible

        if (r < 2) {
            // n_new = relu(n@WnT + (e0[j]+e1[j-1]+e2[j])@WnB + bn); a_nj still in regs
            half8 e0n = *(const half8*)&sb[1][base * P + q * 8];
            half8 e1m = *(const half8*)&sb[2][(base - 1) * P + q * 8];
            half8 e2n = *(const half8*)&sb[3][base * P + q * 8];
            half8 as = e0n + e1m + e2n;        // v_pk_add_f16
            f4v n0 = {bnv0, bnv0, bnv0, bnv0}, n1 = {bnv1, bnv1, bnv1, bnv1};
            n0 = MFMA16(a_nj, fWnT[0], n0); n1 = MFMA16(a_nj, fWnT[1], n1);
            n0 = MFMA16(as,   fWnB[0], n0); n1 = MFMA16(as,   fWnB[1], n1);
            // no barrier needed: nobody reads sb[0] between here and the write barrier
#pragma unroll
            for (int rg = 0; rg < 4; ++rg) {
                int row = wv * 16 + q * 4 + rg + 1;
                *(h2v*)&sb[0][row * P + 2 * m] = pk2(fmaxf(n0[rg], 0.f), fmaxf(n1[rg], 0.f));
            }
            __syncthreads();   // new n visible
        }
    }

    // ---- bi-edge average + decoder layer 1 -> sb[1] (e0 dead) ----
    {
        half8 e1n = *(const half8*)&sb[2][base * P + q * 8];
        half8 e2n = *(const half8*)&sb[3][base * P + q * 8];
        half8 av = (e1n + e2n) * (_Float16)0.5f;
        f4v h0 = {b1v0, b1v0, b1v0, b1v0}, h1 = {b1v1, b1v1, b1v1, b1v1};
        h0 = MFMA16(av, fW1[0], h0); h1 = MFMA16(av, fW1[1], h1);
#pragma unroll
        for (int rg = 0; rg < 4; ++rg) {
            int row = wv * 16 + q * 4 + rg + 1;
            *(h2v*)&sb[1][row * P + 2 * m] = pk2(fmaxf(h0[rg], 0.f), fmaxf(h1[rg], 0.f));
        }
    }
    __syncthreads();

    // ---- decoder layer 2 + masked outputs (ring masks hardcoded) ----
    if (tid < NB) {
        const int g = s0 + tid;
        if (g < NN) {
            const _Float16* hrow = &sb[1][(tid + 4) * P];
            float dec = edb2[0];
#pragma unroll
            for (int i = 0; i < 16; ++i) {
                h2v v = *(const h2v*)&hrow[2 * i];
                dec = fmaf((float)v[0], edW2[i],      dec);
                dec = fmaf((float)v[1], edW2[i + 16], dec);
            }
            dec *= norm;

            float* dataO = out;
            float* rowsO = out + EE;
            float* colsO = out + 2 * EE;
            // self edge g: s=r=g -> mask true, value overridden by sqrt(lhs)
            dataO[g] = sqrtf(lhs_edges[g]);
            rowsO[g] = (float)g;
            colsO[g] = (float)g;
            const bool wrap = (g == NN - 1);
            // fwd edge N+g: s=g, r=(g+1)%N -> mask only at wrap
            int k1 = NN + g;
            dataO[k1] = wrap ? dec : 0.f;
            rowsO[k1] = wrap ? (float)g : 0.f;
            colsO[k1] = 0.f;
            // bwd edge 2N+g: s=(g+1)%N, r=g -> mask except wrap
            int k2 = 2 * NN + g;
            dataO[k2] = wrap ? 0.f : dec;
            rowsO[k2] = wrap ? 0.f : (float)(g + 1);
            colsO[k2] = wrap ? 0.f : (float)g;
        }
    }
}

extern "C" void kernel_launch(void* const* d_in, const int* in_sizes, int n_in,
                              void* d_out, int out_size, void* d_ws, size_t ws_size,
                              hipStream_t stream) {
    const float* nodes     = (const float*)d_in[0];
    const float* edges     = (const float*)d_in[1];
    const float* lhs_edges = (const float*)d_in[5];
    const float* neW1 = (const float*)d_in[9];
    const float* neb1 = (const float*)d_in[10];
    const float* neW2 = (const float*)d_in[11];
    const float* neb2 = (const float*)d_in[12];
    const float* eeW1 = (const float*)d_in[13];
    const float* eeb1 = (const float*)d_in[14];
    const float* eeW2 = (const float*)d_in[15];
    const float* eeb2 = (const float*)d_in[16];
    const float* mpWe = (const float*)d_in[17];
    const float* mpbe = (const float*)d_in[18];
    const float* mpWn = (const float*)d_in[19];
    const float* mpbn = (const float*)d_in[20];
    const float* edW1 = (const float*)d_in[21];
    const float* edb1 = (const float*)d_in[22];
    const float* edW2 = (const float*)d_in[23];
    const float* edb2 = (const float*)d_in[24];

    float* ws   = (float*)d_ws;
    float* outp = (float*)d_out;

    hipLaunchKernelGGL(setup_kernel, dim3(36), dim3(256), 0, stream,
                       mpWe, mpWn, edW1, neW2, eeW2, ws);
    hipLaunchKernelGGL(sumsq_kernel, dim3(EE / 1024), dim3(256), 0, stream,
                       (const float4*)edges, ws);
    hipLaunchKernelGGL(gnn_kernel, dim3(NBLK), dim3(512), 0, stream,
                       nodes, edges, lhs_edges,
                       neW1, neb1, neb2, eeW1, eeb1, eeb2,
                       mpbe, mpbn, edb1, edb2, edW2,
                       ws, outp);
}

// Round 5
// 190.552 us; speedup vs baseline: 7.6507x; 1.0099x over previous
//
#include <hip/hip_runtime.h>

#define NN 262144
#define EE (3 * NN)
#define NB 122              // useful nodes per block
#define RP 130              // phys rows: 1 guard + 128 + 1 guard
#define P 40                // LDS row pitch in halves (80 B)
#define NBLK ((NN + NB - 1) / NB)   // 2149

typedef _Float16 half8 __attribute__((ext_vector_type(8)));
typedef _Float16 h2v   __attribute__((ext_vector_type(2)));
typedef float    f4v   __attribute__((ext_vector_type(4)));

#define MFMA16(a, b, c) __builtin_amdgcn_mfma_f32_16x16x32_f16((a), (b), (c), 0, 0, 0)

static __device__ __forceinline__ h2v pk2(float a, float b) {
    return __builtin_bit_cast(h2v, __builtin_amdgcn_cvt_pkrtz(a, b));
}

// slot s holds original feature forig(s); pairs (2m,2m+1) = orig (m, m+16)
__host__ __device__ __forceinline__ int forig(int p) { return (p >> 1) + 16 * (p & 1); }

// ws: float norm_acc @0; f16 wt @byte16:
//  [0,3072)    We'   frag[c][p], p = K-slot over 96 (per-32 permuted)
//  [3072,4096) WeSum = We[32:64]+We[64:96] (self-edge fold)
//  [4096,5120) WnTop   [5120,6144) WnBot
//  [6144,7168) edW1'   [7168,8192) neW2'   [8192,9216) eeW2'
__global__ __launch_bounds__(256) void setup_kernel(
    const float* __restrict__ mpWe, const float* __restrict__ mpWn,
    const float* __restrict__ edW1, const float* __restrict__ neW2,
    const float* __restrict__ eeW2, float* __restrict__ ws) {
    int i = blockIdx.x * 256 + threadIdx.x;
    if (i == 0) ws[0] = 0.f;
    if (i >= 9216) return;
    _Float16* wt = (_Float16*)((char*)ws + 16);
    float v;
    if (i < 3072)      { int c = i / 96, p = i % 96; int k = (p >> 5) * 32 + forig(p & 31); v = mpWe[k * 32 + c]; }
    else if (i < 4096) { int j = i - 3072, c = j / 32, p = j % 32; int fo = forig(p);
                         v = mpWe[(32 + fo) * 32 + c] + mpWe[(64 + fo) * 32 + c]; }
    else if (i < 5120) { int j = i - 4096, c = j / 32, p = j % 32; v = mpWn[forig(p) * 32 + c]; }
    else if (i < 6144) { int j = i - 5120, c = j / 32, p = j % 32; v = mpWn[(32 + forig(p)) * 32 + c]; }
    else if (i < 7168) { int j = i - 6144, c = j / 32, p = j % 32; v = edW1[forig(p) * 32 + c]; }
    else if (i < 8192) { int j = i - 7168, c = j / 32, p = j % 32; v = neW2[forig(p) * 32 + c]; }
    else               { int j = i - 8192, c = j / 32, p = j % 32; v = eeW2[forig(p) * 32 + c]; }
    wt[i] = (_Float16)v;
}

// prep: sumsq(edges) reduction + all GNN-independent output stores (coalesced).
// Runs after setup (ws[0]=0 guaranteed by stream order), before gnn.
__global__ __launch_bounds__(256) void prep_kernel(
    const float4* __restrict__ e4, const float4* __restrict__ lhs4,
    float* __restrict__ out, float* __restrict__ ws) {
    int t = blockIdx.x * blockDim.x + threadIdx.x;   // EE/4 threads exactly
    float4 v = e4[t];
    float s = v.x * v.x + v.y * v.y + v.z * v.z + v.w * v.w;
#pragma unroll
    for (int off = 32; off > 0; off >>= 1) s += __shfl_down(s, off, 64);
    if ((threadIdx.x & 63) == 0) atomicAdd(ws, s);

    const int NQ = NN / 4;
    if (t < NQ) {
        float4* dataO4 = (float4*)out;
        float4* rowsO4 = (float4*)(out + EE);
        float4* colsO4 = (float4*)(out + 2 * EE);
        float4 l = lhs4[t];
        float4 dq = {sqrtf(l.x), sqrtf(l.y), sqrtf(l.z), sqrtf(l.w)};
        float4 z = {0.f, 0.f, 0.f, 0.f};
        float g0 = (float)(4 * t);
        float4 idx = {g0, g0 + 1.f, g0 + 2.f, g0 + 3.f};
        // self edges [0,N): data=sqrt(lhs), rows=cols=g
        dataO4[t] = dq; rowsO4[t] = idx; colsO4[t] = idx;
        // fwd edges [N,2N): masked out (except wrap, gnn fixes): all zeros
        dataO4[NQ + t] = z; rowsO4[NQ + t] = z; colsO4[NQ + t] = z;
        // bwd edges [2N,3N): rows=g+1, cols=g (wrap element -> 0); data from gnn
        float4 r2v = {g0 + 1.f, g0 + 2.f, g0 + 3.f, g0 + 4.f};
        float4 c2v = idx;
        if (t == NQ - 1) { r2v.w = 0.f; c2v.w = 0.f; }
        rowsO4[2 * NQ + t] = r2v; colsO4[2 * NQ + t] = c2v;
    }
}

// buffers: 0=n, 1=e0(self), 2=e1(fwd i->i+1), 3=e2(bwd i+1->i)
// phys row = logical j + 1; logical j <-> global node s0 - 3 + j
// Hazard model: e-buffer reads are wave-private (own rows only) -> in-place
// writes need NO pre-barrier. Barriers only where cross-wave: after e' writes
// (node reads e1'[j-1]), after n' writes (next round reads n[j+1]), before
// the scalar decoder.
__global__ __launch_bounds__(512, 4) void gnn_kernel(
    const float* __restrict__ nodes, const float* __restrict__ edges,
    const float* __restrict__ neW1, const float* __restrict__ neb1, const float* __restrict__ neb2,
    const float* __restrict__ eeW1, const float* __restrict__ eeb1, const float* __restrict__ eeb2,
    const float* __restrict__ mpbe, const float* __restrict__ mpbn,
    const float* __restrict__ edb1, const float* __restrict__ edb2,
    const float* __restrict__ edW2,
    const float* __restrict__ ws, float* __restrict__ out)
{
    __shared__ __align__(16) _Float16 sb[4][RP * P];

    const int tid  = threadIdx.x;
    const int lane = tid & 63;
    const int wv   = __builtin_amdgcn_readfirstlane(tid >> 6);
    const int q    = lane >> 4;
    const int m    = lane & 15;
    const int s0   = blockIdx.x * NB;

    const float norm = sqrtf(ws[0]);
    const float inv_norm = 1.f / norm;
    const _Float16* wt = (const _Float16*)((const char*)ws + 16);

    // ---- encoder layer 1: thread -> (buffer tid>>7, logical row tid&127) ----
    {
        int b = tid >> 7, r = tid & 127;
        int g = s0 - 3 + r;
        int gm = g < 0 ? g + NN : (g >= NN ? g - NN : g);
        float x; const float *W1, *B1;
        if (b == 0) { x = nodes[gm]; W1 = neW1; B1 = neb1; }
        else        { x = edges[(b - 1) * NN + gm] * inv_norm; W1 = eeW1; B1 = eeb1; }
        _Float16* dst = &sb[b][(r + 1) * P];
#pragma unroll
        for (int blk = 0; blk < 4; ++blk) {
            union { half8 h8; h2v h2[4]; } u;
#pragma unroll
            for (int tt = 0; tt < 4; ++tt) {
                int i = blk * 4 + tt;
                float a0 = fmaxf(fmaf(x, W1[i],      B1[i]),      0.f);
                float a1 = fmaxf(fmaf(x, W1[i + 16], B1[i + 16]), 0.f);
                u.h2[tt] = pk2(a0, a1);
            }
            *(half8*)&dst[blk * 8] = u.h8;
        }
    }
    // zero guard rows (phys 0 and RP-1) of all 4 buffers: 40 b128 writes
    if (tid < 40) {
        int b = tid / 10, k = tid % 10;
        int row = (k < 5) ? 0 : (RP - 1);
        half8 z = {};
        *(half8*)&sb[b][row * P + (k % 5) * 8] = z;
    }
    __syncthreads();   // B1: enc1 visible

    // ---- encoder layer 2 (MFMA, in-place, no relu) ----
    {
        half8 fne0 = *(const half8*)(wt + 7168 + m * 32 + q * 8);
        half8 fne1 = *(const half8*)(wt + 7168 + (16 + m) * 32 + q * 8);
        half8 fee0 = *(const half8*)(wt + 8192 + m * 32 + q * 8);
        half8 fee1 = *(const half8*)(wt + 8192 + (16 + m) * 32 + q * 8);
        float bn0 = neb2[m], bn1 = neb2[16 + m];
        float be0 = eeb2[m], be1 = eeb2[16 + m];
#pragma unroll
        for (int b = 0; b < 4; ++b) {
            _Float16* buf = sb[b];
            half8 a = *(const half8*)&buf[(wv * 16 + m + 1) * P + q * 8];
            float bb0 = b ? be0 : bn0, bb1 = b ? be1 : bn1;
            f4v c0 = {bb0, bb0, bb0, bb0};
            f4v c1 = {bb1, bb1, bb1, bb1};
            c0 = MFMA16(a, b ? fee0 : fne0, c0);
            c1 = MFMA16(a, b ? fee1 : fne1, c1);
#pragma unroll
            for (int rg = 0; rg < 4; ++rg) {
                int row = wv * 16 + q * 4 + rg + 1;
                *(h2v*)&buf[row * P + 2 * m] = pk2(c0[rg], c1[rg]);
            }
        }
    }

    // ---- resident B-fragments + per-lane biases ----
    half8 fWe[3][2], fWeS[2], fWnT[2], fWnB[2], fW1[2];
#pragma unroll
    for (int s = 0; s < 3; ++s)
#pragma unroll
        for (int ct = 0; ct < 2; ++ct)
            fWe[s][ct] = *(const half8*)(wt + (ct * 16 + m) * 96 + s * 32 + q * 8);
#pragma unroll
    for (int ct = 0; ct < 2; ++ct) {
        fWeS[ct] = *(const half8*)(wt + 3072 + (ct * 16 + m) * 32 + q * 8);
        fWnT[ct] = *(const half8*)(wt + 4096 + (ct * 16 + m) * 32 + q * 8);
        fWnB[ct] = *(const half8*)(wt + 5120 + (ct * 16 + m) * 32 + q * 8);
        fW1[ct]  = *(const half8*)(wt + 6144 + (ct * 16 + m) * 32 + q * 8);
    }
    const float bev0 = mpbe[m], bev1 = mpbe[16 + m];
    const float bnv0 = mpbn[m], bnv1 = mpbn[16 + m];
    const float b1v0 = edb1[m], b1v1 = edb1[16 + m];

    __syncthreads();   // B2: enc2 n-values visible (round 0 reads n[j+1] cross-wave)

    const int base = wv * 16 + m + 1;     // phys row of this lane's A-row j

    // ---- rounds 0,1: full edge + node update ----
    for (int r = 0; r < 2; ++r) {
        half8 a_e0 = *(const half8*)&sb[1][base * P + q * 8];
        half8 a_e1 = *(const half8*)&sb[2][base * P + q * 8];
        half8 a_e2 = *(const half8*)&sb[3][base * P + q * 8];
        half8 a_nj  = *(const half8*)&sb[0][base * P + q * 8];
        half8 a_nj1 = *(const half8*)&sb[0][(base + 1) * P + q * 8];
        f4v acc0 = {bev0, bev0, bev0, bev0}, acc1 = {bev1, bev1, bev1, bev1};
        f4v acc2 = acc0, acc3 = acc1, acc4 = acc0, acc5 = acc1;
        // t0 (self): e0@We_e + n[j]@WeSum
        acc0 = MFMA16(a_e0, fWe[0][0], acc0); acc1 = MFMA16(a_e0, fWe[0][1], acc1);
        acc0 = MFMA16(a_nj, fWeS[0],   acc0); acc1 = MFMA16(a_nj, fWeS[1],   acc1);
        // t1 (fwd j->j+1): e1@We_e + n[j]@We_s + n[j+1]@We_r
        acc2 = MFMA16(a_e1,  fWe[0][0], acc2); acc3 = MFMA16(a_e1,  fWe[0][1], acc3);
        acc2 = MFMA16(a_nj,  fWe[1][0], acc2); acc3 = MFMA16(a_nj,  fWe[1][1], acc3);
        acc2 = MFMA16(a_nj1, fWe[2][0], acc2); acc3 = MFMA16(a_nj1, fWe[2][1], acc3);
        // t2 (bwd j+1->j): e2@We_e + n[j+1]@We_s + n[j]@We_r
        acc4 = MFMA16(a_e2,  fWe[0][0], acc4); acc5 = MFMA16(a_e2,  fWe[0][1], acc5);
        acc4 = MFMA16(a_nj1, fWe[1][0], acc4); acc5 = MFMA16(a_nj1, fWe[1][1], acc5);
        acc4 = MFMA16(a_nj,  fWe[2][0], acc4); acc5 = MFMA16(a_nj,  fWe[2][1], acc5);
        // in-place e' writes: e-reads were wave-private -> no barrier needed first
#pragma unroll
        for (int rg = 0; rg < 4; ++rg) {
            int row = wv * 16 + q * 4 + rg + 1;
            *(h2v*)&sb[1][row * P + 2 * m] = pk2(fmaxf(acc0[rg], 0.f), fmaxf(acc1[rg], 0.f));
            *(h2v*)&sb[2][row * P + 2 * m] = pk2(fmaxf(acc2[rg], 0.f), fmaxf(acc3[rg], 0.f));
            *(h2v*)&sb[3][row * P + 2 * m] = pk2(fmaxf(acc4[rg], 0.f), fmaxf(acc5[rg], 0.f));
        }
        __syncthreads();   // new e visible (node needs e1'[j-1] cross-wave)

        // n_new = relu(n@WnT + (e0'[j]+e1'[j-1]+e2'[j])@WnB + bn); a_nj still live
        half8 e0n = *(const half8*)&sb[1][base * P + q * 8];
        half8 e1m = *(const half8*)&sb[2][(base - 1) * P + q * 8];
        half8 e2n = *(const half8*)&sb[3][base * P + q * 8];
        half8 as = e0n + e1m + e2n;
        f4v n0 = {bnv0, bnv0, bnv0, bnv0}, n1 = {bnv1, bnv1, bnv1, bnv1};
        n0 = MFMA16(a_nj, fWnT[0], n0); n1 = MFMA16(a_nj, fWnT[1], n1);
        n0 = MFMA16(as,   fWnB[0], n0); n1 = MFMA16(as,   fWnB[1], n1);
        // in-place n write safe: all cross-wave n-reads happened before prev barrier
#pragma unroll
        for (int rg = 0; rg < 4; ++rg) {
            int row = wv * 16 + q * 4 + rg + 1;
            *(h2v*)&sb[0][row * P + 2 * m] = pk2(fmaxf(n0[rg], 0.f), fmaxf(n1[rg], 0.f));
        }
        __syncthreads();   // new n visible
    }

    // ---- round 2: only e1,e2 needed (e0 output is overwritten at diag) ----
    {
        half8 a_e1 = *(const half8*)&sb[2][base * P + q * 8];
        half8 a_e2 = *(const half8*)&sb[3][base * P + q * 8];
        half8 a_nj  = *(const half8*)&sb[0][base * P + q * 8];
        half8 a_nj1 = *(const half8*)&sb[0][(base + 1) * P + q * 8];
        f4v acc2 = {bev0, bev0, bev0, bev0}, acc3 = {bev1, bev1, bev1, bev1};
        f4v acc4 = acc2, acc5 = acc3;
        acc2 = MFMA16(a_e1,  fWe[0][0], acc2); acc3 = MFMA16(a_e1,  fWe[0][1], acc3);
        acc2 = MFMA16(a_nj,  fWe[1][0], acc2); acc3 = MFMA16(a_nj,  fWe[1][1], acc3);
        acc2 = MFMA16(a_nj1, fWe[2][0], acc2); acc3 = MFMA16(a_nj1, fWe[2][1], acc3);
        acc4 = MFMA16(a_e2,  fWe[0][0], acc4); acc5 = MFMA16(a_e2,  fWe[0][1], acc5);
        acc4 = MFMA16(a_nj1, fWe[1][0], acc4); acc5 = MFMA16(a_nj1, fWe[1][1], acc5);
        acc4 = MFMA16(a_nj,  fWe[2][0], acc4); acc5 = MFMA16(a_nj,  fWe[2][1], acc5);
        // bi-edge average in C-regs (relu then 0.5*(e1+e2)), single relayout
#pragma unroll
        for (int rg = 0; rg < 4; ++rg) {
            int row = wv * 16 + q * 4 + rg + 1;
            float av0 = 0.5f * (fmaxf(acc2[rg], 0.f) + fmaxf(acc4[rg], 0.f));
            float av1 = 0.5f * (fmaxf(acc3[rg], 0.f) + fmaxf(acc5[rg], 0.f));
            *(h2v*)&sb[1][row * P + 2 * m] = pk2(av0, av1);
        }
        // no barrier: decoder L1 reads own rows only (own-wave writes)
    }

    // ---- decoder layer 1 (MFMA): h = relu(avg @ edW1 + edb1) -> sb[2] ----
    {
        half8 av = *(const half8*)&sb[1][base * P + q * 8];
        f4v h0 = {b1v0, b1v0, b1v0, b1v0}, h1 = {b1v1, b1v1, b1v1, b1v1};
        h0 = MFMA16(av, fW1[0], h0); h1 = MFMA16(av, fW1[1], h1);
#pragma unroll
        for (int rg = 0; rg < 4; ++rg) {
            int row = wv * 16 + q * 4 + rg + 1;
            *(h2v*)&sb[2][row * P + 2 * m] = pk2(fmaxf(h0[rg], 0.f), fmaxf(h1[rg], 0.f));
        }
    }
    __syncthreads();   // decoder L2 reads cross-wave rows

    // ---- decoder layer 2 + the only GNN-dependent stores ----
    if (tid < NB) {
        const int g = s0 + tid;
        if (g < NN) {
            const _Float16* hrow = &sb[2][(tid + 4) * P];
            float dec = edb2[0];
#pragma unroll
            for (int i = 0; i < 16; ++i) {
                h2v v = *(const h2v*)&hrow[2 * i];
                dec = fmaf((float)v[0], edW2[i],      dec);
                dec = fmaf((float)v[1], edW2[i + 16], dec);
            }
            dec *= norm;
            const bool wrap = (g == NN - 1);
            // bwd edge 2N+g: data = dec (masked out at wrap)
            out[2 * NN + g] = wrap ? 0.f : dec;
            if (wrap) {   // fwd wrap edge N+g = 2N-1: mask true here
                out[2 * NN - 1] = dec;            // dataO
                out[EE + 2 * NN - 1] = (float)g;  // rowsO (colsO=0 from prep)
            }
        }
    }
}

extern "C" void kernel_launch(void* const* d_in, const int* in_sizes, int n_in,
                              void* d_out, int out_size, void* d_ws, size_t ws_size,
                              hipStream_t stream) {
    const float* nodes     = (const float*)d_in[0];
    const float* edges     = (const float*)d_in[1];
    const float* lhs_edges = (const float*)d_in[5];
    const float* neW1 = (const float*)d_in[9];
    const float* neb1 = (const float*)d_in[10];
    const float* neW2 = (const float*)d_in[11];
    const float* neb2 = (const float*)d_in[12];
    const float* eeW1 = (const float*)d_in[13];
    const float* eeb1 = (const float*)d_in[14];
    const float* eeW2 = (const float*)d_in[15];
    const float* eeb2 = (const float*)d_in[16];
    const float* mpWe = (const float*)d_in[17];
    const float* mpbe = (const float*)d_in[18];
    const float* mpWn = (const float*)d_in[19];
    const float* mpbn = (const float*)d_in[20];
    const float* edW1 = (const float*)d_in[21];
    const float* edb1 = (const float*)d_in[22];
    const float* edW2 = (const float*)d_in[23];
    const float* edb2 = (const float*)d_in[24];

    float* ws   = (float*)d_ws;
    float* outp = (float*)d_out;

    hipLaunchKernelGGL(setup_kernel, dim3(36), dim3(256), 0, stream,
                       mpWe, mpWn, edW1, neW2, eeW2, ws);
    hipLaunchKernelGGL(prep_kernel, dim3(EE / 1024), dim3(256), 0, stream,
                       (const float4*)edges, (const float4*)lhs_edges, outp, ws);
    hipLaunchKernelGGL(gnn_kernel, dim3(NBLK), dim3(512), 0, stream,
                       nodes, edges,
                       neW1, neb1, neb2, eeW1, eeb1, eeb2,
                       mpbe, mpbn, edb1, edb2, edW2,
                       ws, outp);
}

// Round 6
// 155.725 us; speedup vs baseline: 9.3617x; 1.2236x over previous
//
#include <hip/hip_runtime.h>

#define NN 262144
#define EE (3 * NN)
#define NB 122              // useful nodes per block
#define RP 130              // phys rows: 1 guard + 128 + 1 guard
#define P 40                // LDS row pitch in halves (80 B)
#define NBLK ((NN + NB - 1) / NB)   // 2149
#define SUMB 128            // partial-sum blocks (atomic-free reduction)

typedef _Float16 half8 __attribute__((ext_vector_type(8)));
typedef _Float16 h2v   __attribute__((ext_vector_type(2)));
typedef float    f4v   __attribute__((ext_vector_type(4)));

#define MFMA16(a, b, c) __builtin_amdgcn_mfma_f32_16x16x32_f16((a), (b), (c), 0, 0, 0)

static __device__ __forceinline__ h2v pk2(float a, float b) {
    return __builtin_bit_cast(h2v, __builtin_amdgcn_cvt_pkrtz(a, b));
}

// slot s holds original feature forig(s); pairs (2m,2m+1) = orig (m, m+16)
__host__ __device__ __forceinline__ int forig(int p) { return (p >> 1) + 16 * (p & 1); }

// ws: float partials[128] @ byte 0; f16 wt @ byte 512:
//  [0,3072)    We'   frag[c][p], p = K-slot over 96 (per-32 permuted)
//  [3072,4096) WeSum = We[32:64]+We[64:96] (self-edge fold)
//  [4096,5120) WnTop   [5120,6144) WnBot
//  [6144,7168) edW1'   [7168,8192) neW2'   [8192,9216) eeW2'
//
// prep2: weight transform (gid<9216) + atomic-free sumsq partials.
__global__ __launch_bounds__(256) void prep2_kernel(
    const float* __restrict__ mpWe, const float* __restrict__ mpWn,
    const float* __restrict__ edW1, const float* __restrict__ neW2,
    const float* __restrict__ eeW2, const float4* __restrict__ e4,
    float* __restrict__ ws) {
    const int gid = blockIdx.x * 256 + threadIdx.x;

    // ---- weight transform ----
    if (gid < 9216) {
        _Float16* wt = (_Float16*)((char*)ws + 512);
        int i = gid;
        float v;
        if (i < 3072)      { int c = i / 96, p = i % 96; int k = (p >> 5) * 32 + forig(p & 31); v = mpWe[k * 32 + c]; }
        else if (i < 4096) { int j = i - 3072, c = j / 32, p = j % 32; int fo = forig(p);
                             v = mpWe[(32 + fo) * 32 + c] + mpWe[(64 + fo) * 32 + c]; }
        else if (i < 5120) { int j = i - 4096, c = j / 32, p = j % 32; v = mpWn[forig(p) * 32 + c]; }
        else if (i < 6144) { int j = i - 5120, c = j / 32, p = j % 32; v = mpWn[(32 + forig(p)) * 32 + c]; }
        else if (i < 7168) { int j = i - 6144, c = j / 32, p = j % 32; v = edW1[forig(p) * 32 + c]; }
        else if (i < 8192) { int j = i - 7168, c = j / 32, p = j % 32; v = neW2[forig(p) * 32 + c]; }
        else               { int j = i - 8192, c = j / 32, p = j % 32; v = eeW2[forig(p) * 32 + c]; }
        wt[i] = (_Float16)v;
    }

    // ---- sumsq(edges): grid-stride, per-block partial -> ws[blockIdx] ----
    float s = 0.f;
#pragma unroll
    for (int k = 0; k < 6; ++k) {               // 128*256*6 = 196608 = EE/4 exactly
        float4 v = e4[gid + k * (SUMB * 256)];
        s += v.x * v.x + v.y * v.y + v.z * v.z + v.w * v.w;
    }
#pragma unroll
    for (int off = 32; off > 0; off >>= 1) s += __shfl_down(s, off, 64);
    __shared__ float red[4];
    if ((threadIdx.x & 63) == 0) red[threadIdx.x >> 6] = s;
    __syncthreads();
    if (threadIdx.x == 0) ws[blockIdx.x] = red[0] + red[1] + red[2] + red[3];
}

// buffers: 0=n, 1=e0(self), 2=e1(fwd i->i+1), 3=e2(bwd i+1->i)
// phys row = logical j + 1; logical j <-> global node s0 - 3 + j
// Hazard model: e-buffer reads are wave-private -> in-place writes need no
// pre-barrier; barriers only at cross-wave visibility points.
__global__ __launch_bounds__(512, 4) void gnn_kernel(
    const float* __restrict__ nodes, const float* __restrict__ edges,
    const float* __restrict__ lhs_edges,
    const float* __restrict__ neW1, const float* __restrict__ neb1, const float* __restrict__ neb2,
    const float* __restrict__ eeW1, const float* __restrict__ eeb1, const float* __restrict__ eeb2,
    const float* __restrict__ mpbe, const float* __restrict__ mpbn,
    const float* __restrict__ edb1, const float* __restrict__ edb2,
    const float* __restrict__ edW2,
    const float* __restrict__ ws, float* __restrict__ out)
{
    __shared__ __align__(16) _Float16 sb[4][RP * P];

    const int tid  = threadIdx.x;
    const int lane = tid & 63;
    const int wv   = __builtin_amdgcn_readfirstlane(tid >> 6);
    const int q    = lane >> 4;
    const int m    = lane & 15;
    const int s0   = blockIdx.x * NB;

    // norm from the 128 partials (uniform scalar loads; 4 chains to cut latency)
    float ssa = 0.f, ssb = 0.f, ssc = 0.f, ssd = 0.f;
#pragma unroll
    for (int i = 0; i < SUMB; i += 4) {
        ssa += ws[i]; ssb += ws[i + 1]; ssc += ws[i + 2]; ssd += ws[i + 3];
    }
    const float norm = sqrtf((ssa + ssb) + (ssc + ssd));
    const float inv_norm = 1.f / norm;
    const _Float16* wt = (const _Float16*)((const char*)ws + 512);

    // ---- encoder layer 1: thread -> (buffer tid>>7, logical row tid&127) ----
    {
        int b = tid >> 7, r = tid & 127;
        int g = s0 - 3 + r;
        int gm = g < 0 ? g + NN : (g >= NN ? g - NN : g);
        float x; const float *W1, *B1;
        if (b == 0) { x = nodes[gm]; W1 = neW1; B1 = neb1; }
        else        { x = edges[(b - 1) * NN + gm] * inv_norm; W1 = eeW1; B1 = eeb1; }
        _Float16* dst = &sb[b][(r + 1) * P];
#pragma unroll
        for (int blk = 0; blk < 4; ++blk) {
            union { half8 h8; h2v h2[4]; } u;
#pragma unroll
            for (int tt = 0; tt < 4; ++tt) {
                int i = blk * 4 + tt;
                float a0 = fmaxf(fmaf(x, W1[i],      B1[i]),      0.f);
                float a1 = fmaxf(fmaf(x, W1[i + 16], B1[i + 16]), 0.f);
                u.h2[tt] = pk2(a0, a1);
            }
            *(half8*)&dst[blk * 8] = u.h8;
        }
    }
    // zero guard rows (phys 0 and RP-1) of all 4 buffers: 40 b128 writes
    if (tid < 40) {
        int b = tid / 10, k = tid % 10;
        int row = (k < 5) ? 0 : (RP - 1);
        half8 z = {};
        *(half8*)&sb[b][row * P + (k % 5) * 8] = z;
    }

    // ---- GNN-independent output stores (fire-and-forget, overlap with MFMA) ----
    if (tid < NB) {
        const int g = s0 + tid;
        if (g < NN) {
            float* dataO = out;
            float* rowsO = out + EE;
            float* colsO = out + 2 * EE;
            const bool wrap = (g == NN - 1);
            // self edge g: data=sqrt(lhs), rows=cols=g
            dataO[g] = sqrtf(lhs_edges[g]);
            rowsO[g] = (float)g; colsO[g] = (float)g;
            // fwd edge N+g: masked out except wrap (decoder tail fixes wrap)
            dataO[NN + g] = 0.f; rowsO[NN + g] = 0.f; colsO[NN + g] = 0.f;
            // bwd edge 2N+g: rows=g+1, cols=g (wrap -> 0); data from decoder
            rowsO[2 * NN + g] = wrap ? 0.f : (float)(g + 1);
            colsO[2 * NN + g] = wrap ? 0.f : (float)g;
        }
    }
    __syncthreads();   // B1: enc1 visible

    // ---- encoder layer 2 (MFMA, in-place, no relu) ----
    {
        half8 fne0 = *(const half8*)(wt + 7168 + m * 32 + q * 8);
        half8 fne1 = *(const half8*)(wt + 7168 + (16 + m) * 32 + q * 8);
        half8 fee0 = *(const half8*)(wt + 8192 + m * 32 + q * 8);
        half8 fee1 = *(const half8*)(wt + 8192 + (16 + m) * 32 + q * 8);
        float bn0 = neb2[m], bn1 = neb2[16 + m];
        float be0 = eeb2[m], be1 = eeb2[16 + m];
#pragma unroll
        for (int b = 0; b < 4; ++b) {
            _Float16* buf = sb[b];
            half8 a = *(const half8*)&buf[(wv * 16 + m + 1) * P + q * 8];
            float bb0 = b ? be0 : bn0, bb1 = b ? be1 : bn1;
            f4v c0 = {bb0, bb0, bb0, bb0};
            f4v c1 = {bb1, bb1, bb1, bb1};
            c0 = MFMA16(a, b ? fee0 : fne0, c0);
            c1 = MFMA16(a, b ? fee1 : fne1, c1);
#pragma unroll
            for (int rg = 0; rg < 4; ++rg) {
                int row = wv * 16 + q * 4 + rg + 1;
                *(h2v*)&buf[row * P + 2 * m] = pk2(c0[rg], c1[rg]);
            }
        }
    }

    // ---- resident B-fragments + per-lane biases ----
    half8 fWe[3][2], fWeS[2], fWnT[2], fWnB[2], fW1[2];
#pragma unroll
    for (int s = 0; s < 3; ++s)
#pragma unroll
        for (int ct = 0; ct < 2; ++ct)
            fWe[s][ct] = *(const half8*)(wt + (ct * 16 + m) * 96 + s * 32 + q * 8);
#pragma unroll
    for (int ct = 0; ct < 2; ++ct) {
        fWeS[ct] = *(const half8*)(wt + 3072 + (ct * 16 + m) * 32 + q * 8);
        fWnT[ct] = *(const half8*)(wt + 4096 + (ct * 16 + m) * 32 + q * 8);
        fWnB[ct] = *(const half8*)(wt + 5120 + (ct * 16 + m) * 32 + q * 8);
        fW1[ct]  = *(const half8*)(wt + 6144 + (ct * 16 + m) * 32 + q * 8);
    }
    const float bev0 = mpbe[m], bev1 = mpbe[16 + m];
    const float bnv0 = mpbn[m], bnv1 = mpbn[16 + m];
    const float b1v0 = edb1[m], b1v1 = edb1[16 + m];

    __syncthreads();   // B2: enc2 n-values visible (round 0 reads n[j+1] cross-wave)

    const int base = wv * 16 + m + 1;     // phys row of this lane's A-row j

    // ---- rounds 0,1: full edge + node update ----
    for (int r = 0; r < 2; ++r) {
        half8 a_e0 = *(const half8*)&sb[1][base * P + q * 8];
        half8 a_e1 = *(const half8*)&sb[2][base * P + q * 8];
        half8 a_e2 = *(const half8*)&sb[3][base * P + q * 8];
        half8 a_nj  = *(const half8*)&sb[0][base * P + q * 8];
        half8 a_nj1 = *(const half8*)&sb[0][(base + 1) * P + q * 8];
        f4v acc0 = {bev0, bev0, bev0, bev0}, acc1 = {bev1, bev1, bev1, bev1};
        f4v acc2 = acc0, acc3 = acc1, acc4 = acc0, acc5 = acc1;
        acc0 = MFMA16(a_e0, fWe[0][0], acc0); acc1 = MFMA16(a_e0, fWe[0][1], acc1);
        acc0 = MFMA16(a_nj, fWeS[0],   acc0); acc1 = MFMA16(a_nj, fWeS[1],   acc1);
        acc2 = MFMA16(a_e1,  fWe[0][0], acc2); acc3 = MFMA16(a_e1,  fWe[0][1], acc3);
        acc2 = MFMA16(a_nj,  fWe[1][0], acc2); acc3 = MFMA16(a_nj,  fWe[1][1], acc3);
        acc2 = MFMA16(a_nj1, fWe[2][0], acc2); acc3 = MFMA16(a_nj1, fWe[2][1], acc3);
        acc4 = MFMA16(a_e2,  fWe[0][0], acc4); acc5 = MFMA16(a_e2,  fWe[0][1], acc5);
        acc4 = MFMA16(a_nj1, fWe[1][0], acc4); acc5 = MFMA16(a_nj1, fWe[1][1], acc5);
        acc4 = MFMA16(a_nj,  fWe[2][0], acc4); acc5 = MFMA16(a_nj,  fWe[2][1], acc5);
#pragma unroll
        for (int rg = 0; rg < 4; ++rg) {
            int row = wv * 16 + q * 4 + rg + 1;
            *(h2v*)&sb[1][row * P + 2 * m] = pk2(fmaxf(acc0[rg], 0.f), fmaxf(acc1[rg], 0.f));
            *(h2v*)&sb[2][row * P + 2 * m] = pk2(fmaxf(acc2[rg], 0.f), fmaxf(acc3[rg], 0.f));
            *(h2v*)&sb[3][row * P + 2 * m] = pk2(fmaxf(acc4[rg], 0.f), fmaxf(acc5[rg], 0.f));
        }
        __syncthreads();   // new e visible (node needs e1'[j-1] cross-wave)

        half8 e0n = *(const half8*)&sb[1][base * P + q * 8];
        half8 e1m = *(const half8*)&sb[2][(base - 1) * P + q * 8];
        half8 e2n = *(const half8*)&sb[3][base * P + q * 8];
        half8 as = e0n + e1m + e2n;
        f4v n0 = {bnv0, bnv0, bnv0, bnv0}, n1 = {bnv1, bnv1, bnv1, bnv1};
        n0 = MFMA16(a_nj, fWnT[0], n0); n1 = MFMA16(a_nj, fWnT[1], n1);
        n0 = MFMA16(as,   fWnB[0], n0); n1 = MFMA16(as,   fWnB[1], n1);
#pragma unroll
        for (int rg = 0; rg < 4; ++rg) {
            int row = wv * 16 + q * 4 + rg + 1;
            *(h2v*)&sb[0][row * P + 2 * m] = pk2(fmaxf(n0[rg], 0.f), fmaxf(n1[rg], 0.f));
        }
        __syncthreads();   // new n visible
    }

    // ---- round 2: only e1,e2 needed (e0 output is overwritten at diag) ----
    {
        half8 a_e1 = *(const half8*)&sb[2][base * P + q * 8];
        half8 a_e2 = *(const half8*)&sb[3][base * P + q * 8];
        half8 a_nj  = *(const half8*)&sb[0][base * P + q * 8];
        half8 a_nj1 = *(const half8*)&sb[0][(base + 1) * P + q * 8];
        f4v acc2 = {bev0, bev0, bev0, bev0}, acc3 = {bev1, bev1, bev1, bev1};
        f4v acc4 = acc2, acc5 = acc3;
        acc2 = MFMA16(a_e1,  fWe[0][0], acc2); acc3 = MFMA16(a_e1,  fWe[0][1], acc3);
        acc2 = MFMA16(a_nj,  fWe[1][0], acc2); acc3 = MFMA16(a_nj,  fWe[1][1], acc3);
        acc2 = MFMA16(a_nj1, fWe[2][0], acc2); acc3 = MFMA16(a_nj1, fWe[2][1], acc3);
        acc4 = MFMA16(a_e2,  fWe[0][0], acc4); acc5 = MFMA16(a_e2,  fWe[0][1], acc5);
        acc4 = MFMA16(a_nj1, fWe[1][0], acc4); acc5 = MFMA16(a_nj1, fWe[1][1], acc5);
        acc4 = MFMA16(a_nj,  fWe[2][0], acc4); acc5 = MFMA16(a_nj,  fWe[2][1], acc5);
        // bi-edge average in C-regs (relu then 0.5*(e1+e2)), single relayout
#pragma unroll
        for (int rg = 0; rg < 4; ++rg) {
            int row = wv * 16 + q * 4 + rg + 1;
            float av0 = 0.5f * (fmaxf(acc2[rg], 0.f) + fmaxf(acc4[rg], 0.f));
            float av1 = 0.5f * (fmaxf(acc3[rg], 0.f) + fmaxf(acc5[rg], 0.f));
            *(h2v*)&sb[1][row * P + 2 * m] = pk2(av0, av1);
        }
        // no barrier: decoder L1 reads own rows only (own-wave writes)
    }

    // ---- decoder layer 1 (MFMA): h = relu(avg @ edW1 + edb1) -> sb[2] ----
    {
        half8 av = *(const half8*)&sb[1][base * P + q * 8];
        f4v h0 = {b1v0, b1v0, b1v0, b1v0}, h1 = {b1v1, b1v1, b1v1, b1v1};
        h0 = MFMA16(av, fW1[0], h0); h1 = MFMA16(av, fW1[1], h1);
#pragma unroll
        for (int rg = 0; rg < 4; ++rg) {
            int row = wv * 16 + q * 4 + rg + 1;
            *(h2v*)&sb[2][row * P + 2 * m] = pk2(fmaxf(h0[rg], 0.f), fmaxf(h1[rg], 0.f));
        }
    }
    __syncthreads();   // decoder L2 reads cross-wave rows

    // ---- decoder layer 2 + the only GNN-dependent stores ----
    if (tid < NB) {
        const int g = s0 + tid;
        if (g < NN) {
            const _Float16* hrow = &sb[2][(tid + 4) * P];
            float dec = edb2[0];
#pragma unroll
            for (int i = 0; i < 16; ++i) {
                h2v v = *(const h2v*)&hrow[2 * i];
                dec = fmaf((float)v[0], edW2[i],      dec);
                dec = fmaf((float)v[1], edW2[i + 16], dec);
            }
            dec *= norm;
            const bool wrap = (g == NN - 1);
            // bwd edge 2N+g: data = dec (masked out at wrap)
            out[2 * NN + g] = wrap ? 0.f : dec;
            if (wrap) {   // fwd wrap edge N+g = 2N-1: mask true here
                out[2 * NN - 1] = dec;            // dataO
                out[EE + 2 * NN - 1] = (float)g;  // rowsO (colsO=0 from static store)
            }
        }
    }
}

extern "C" void kernel_launch(void* const* d_in, const int* in_sizes, int n_in,
                              void* d_out, int out_size, void* d_ws, size_t ws_size,
                              hipStream_t stream) {
    const float* nodes     = (const float*)d_in[0];
    const float* edges     = (const float*)d_in[1];
    const float* lhs_edges = (const float*)d_in[5];
    const float* neW1 = (const float*)d_in[9];
    const float* neb1 = (const float*)d_in[10];
    const float* neW2 = (const float*)d_in[11];
    const float* neb2 = (const float*)d_in[12];
    const float* eeW1 = (const float*)d_in[13];
    const float* eeb1 = (const float*)d_in[14];
    const float* eeW2 = (const float*)d_in[15];
    const float* eeb2 = (const float*)d_in[16];
    const float* mpWe = (const float*)d_in[17];
    const float* mpbe = (const float*)d_in[18];
    const float* mpWn = (const float*)d_in[19];
    const float* mpbn = (const float*)d_in[20];
    const float* edW1 = (const float*)d_in[21];
    const float* edb1 = (const float*)d_in[22];
    const float* edW2 = (const float*)d_in[23];
    const float* edb2 = (const float*)d_in[24];

    float* ws   = (float*)d_ws;
    float* outp = (float*)d_out;

    hipLaunchKernelGGL(prep2_kernel, dim3(SUMB), dim3(256), 0, stream,
                       mpWe, mpWn, edW1, neW2, eeW2, (const float4*)edges, ws);
    hipLaunchKernelGGL(gnn_kernel, dim3(NBLK), dim3(512), 0, stream,
                       nodes, edges, lhs_edges,
                       neW1, neb1, neb2, eeW1, eeb1, eeb2,
                       mpbe, mpbn, edb1, edb2, edW2,
                       ws, outp);
}